// Round 1
// baseline (945.733 us; speedup 1.0000x reference)
//
#include <hip/hip_runtime.h>
#include <math.h>

#define N_POINTS 4000000
#define N_PLANES 64
#define THRESH   0.02f
#define PPT      16   // points held in registers per lane -> 1024 points per wave

// ---------------------------------------------------------------------------
// Kernel 1: per-plane masked moment reduction over the ORIGINAL points.
// Each wave holds 1024 points in registers, loops planes outer, accumulates
// cnt / sum / second moments via ballot + serial set-bit walk (hits ~3.3%).
// Partials combined with f64 global atomics (plane order rotated per block to
// spread same-address atomic contention in time).
// ---------------------------------------------------------------------------
__global__ __launch_bounds__(256)
void reduce_kernel(const float* __restrict__ pts,
                   const float* __restrict__ nrm,
                   const float* __restrict__ dst,
                   double* __restrict__ acc)
{
    const int lane = threadIdx.x & 63;
    const int wid  = threadIdx.x >> 6;
    const long long wave = (long long)blockIdx.x * 4 + wid;
    const long long base = wave * (64LL * PPT);

    float px[PPT], py[PPT], pz[PPT];
#pragma unroll
    for (int j = 0; j < PPT; ++j) {
        long long idx = base + (long long)j * 64 + lane;
        if (idx < N_POINTS) {
            px[j] = pts[idx*3+0];
            py[j] = pts[idx*3+1];
            pz[j] = pts[idx*3+2];
        } else {
            // NaN makes |t| < THRESH false regardless of the plane
            px[j] = __builtin_nanf("");
            py[j] = 0.0f;
            pz[j] = 0.0f;
        }
    }

    const int prot = (int)(blockIdx.x & 63);
    for (int pi = 0; pi < N_PLANES; ++pi) {
        const int p = (pi + prot) & 63;
        const float nx = nrm[p*3+0], ny = nrm[p*3+1], nz = nrm[p*3+2];
        const float d  = dst[p];

        float cnt = 0.0f;
        float sx = 0.0f, sy = 0.0f, sz = 0.0f;
        float xx = 0.0f, xy = 0.0f, xz = 0.0f;
        float yy = 0.0f, yz = 0.0f, zz = 0.0f;

#pragma unroll
        for (int j = 0; j < PPT; ++j) {
            const float t = fmaf(px[j], nx, fmaf(py[j], ny, fmaf(pz[j], nz, -d)));
            unsigned long long bal = __ballot(fabsf(t) < THRESH);
            cnt += (float)__popcll(bal);
            // wave-uniform serial walk over set bits (~2.1 per group)
            while (bal) {
                const int l = __ffsll((long long)bal) - 1;
                bal &= bal - 1ULL;
                const float x = __shfl(px[j], l);
                const float y = __shfl(py[j], l);
                const float z = __shfl(pz[j], l);
                sx += x; sy += y; sz += z;
                xx = fmaf(x, x, xx); xy = fmaf(x, y, xy); xz = fmaf(x, z, xz);
                yy = fmaf(y, y, yy); yz = fmaf(y, z, yz); zz = fmaf(z, z, zz);
            }
        }

        if (lane == 0) {
            double* a = acc + p * 10;
            atomicAdd(a+0, (double)cnt);
            atomicAdd(a+1, (double)sx); atomicAdd(a+2, (double)sy); atomicAdd(a+3, (double)sz);
            atomicAdd(a+4, (double)xx); atomicAdd(a+5, (double)xy); atomicAdd(a+6, (double)xz);
            atomicAdd(a+7, (double)yy); atomicAdd(a+8, (double)yz); atomicAdd(a+9, (double)zz);
        }
    }
}

// ---------------------------------------------------------------------------
// Kernel 2: 64 independent 3x3 symmetric eigensolves (f64 cyclic Jacobi).
// Produces per-plane {rn(3), rd, valid} matching the reference semantics:
// cov from original points, +diag(1,2,3) jitter when cnt<3, eigenvector of
// the SMALLEST eigenvalue, sign-aligned with the input normal.
// ---------------------------------------------------------------------------
__global__ void fit_kernel(const double* __restrict__ acc,
                           const float* __restrict__ nrm,
                           float* __restrict__ params)
{
    const int p = threadIdx.x;
    if (p >= N_PLANES) return;

    const double* a = acc + p * 10;
    const double cnt = a[0];
    const double sx = a[1], sy = a[2], sz = a[3];
    const double den = fmax(cnt, 1.0);
    const double cx = sx / den, cy = sy / den, cz = sz / den;

    double C[3][3];
    C[0][0] = a[4] - 2.0*cx*sx + cnt*cx*cx;
    C[0][1] = a[5] - cx*sy - cy*sx + cnt*cx*cy;
    C[0][2] = a[6] - cx*sz - cz*sx + cnt*cx*cz;
    C[1][1] = a[7] - 2.0*cy*sy + cnt*cy*cy;
    C[1][2] = a[8] - cy*sz - cz*sy + cnt*cy*cz;
    C[2][2] = a[9] - 2.0*cz*sz + cnt*cz*cz;
    C[1][0] = C[0][1]; C[2][0] = C[0][2]; C[2][1] = C[1][2];

    const double valid = (cnt >= 3.0) ? 1.0 : 0.0;
    C[0][0] += (1.0 - valid) * 1.0;
    C[1][1] += (1.0 - valid) * 2.0;
    C[2][2] += (1.0 - valid) * 3.0;

    double V[3][3] = {{1,0,0},{0,1,0},{0,0,1}};
    for (int sweep = 0; sweep < 15; ++sweep) {
#pragma unroll
        for (int k = 0; k < 3; ++k) {
            const int pp = (k == 2) ? 1 : 0;
            const int qq = (k == 0) ? 1 : 2;
            const int rr = 3 - pp - qq;
            const double apq = C[pp][qq];
            if (fabs(apq) < 1e-300) continue;
            const double theta = (C[qq][qq] - C[pp][pp]) / (2.0 * apq);
            const double t = copysign(1.0, theta) / (fabs(theta) + sqrt(theta*theta + 1.0));
            const double c = 1.0 / sqrt(t*t + 1.0);
            const double s = t * c;
            const double app = C[pp][pp], aqq = C[qq][qq];
            const double arp = C[rr][pp], arq = C[rr][qq];
            C[pp][pp] = app - t * apq;
            C[qq][qq] = aqq + t * apq;
            C[pp][qq] = 0.0; C[qq][pp] = 0.0;
            const double nrp = c*arp - s*arq;
            const double nrq = s*arp + c*arq;
            C[rr][pp] = nrp; C[pp][rr] = nrp;
            C[rr][qq] = nrq; C[qq][rr] = nrq;
#pragma unroll
            for (int i = 0; i < 3; ++i) {
                const double vip = V[i][pp], viq = V[i][qq];
                V[i][pp] = c*vip - s*viq;
                V[i][qq] = s*vip + c*viq;
            }
        }
    }

    int idx = 0;
    if (C[1][1] < C[idx][idx]) idx = 1;
    if (C[2][2] < C[idx][idx]) idx = 2;
    double rx = V[0][idx], ry = V[1][idx], rz = V[2][idx];
    const double inv = 1.0 / sqrt(rx*rx + ry*ry + rz*rz);
    rx *= inv; ry *= inv; rz *= inv;

    const double nx = (double)nrm[p*3+0];
    const double ny = (double)nrm[p*3+1];
    const double nz = (double)nrm[p*3+2];
    if (rx*nx + ry*ny + rz*nz < 0.0) { rx = -rx; ry = -ry; rz = -rz; }
    const double rd = cx*rx + cy*ry + cz*rz;

    params[p*8+0] = (float)rx;
    params[p*8+1] = (float)ry;
    params[p*8+2] = (float)rz;
    params[p*8+3] = (float)rd;
    params[p*8+4] = (float)valid;
}

// ---------------------------------------------------------------------------
// Kernel 3: per-point sequential projection across planes 0..63.
// Mask from the ORIGINAL point (same fma expression as kernel 1), projection
// applied to the running point. Wave-uniform skip when no lane is masked.
// ---------------------------------------------------------------------------
__global__ __launch_bounds__(256)
void project_kernel(const float* __restrict__ pts,
                    const float* __restrict__ nrm,
                    const float* __restrict__ dst,
                    const float* __restrict__ params,
                    float* __restrict__ out)
{
    const long long i = (long long)blockIdx.x * 256 + threadIdx.x;
    if (i >= N_POINTS) return;

    const float ox = pts[i*3+0], oy = pts[i*3+1], oz = pts[i*3+2];
    float qx = ox, qy = oy, qz = oz;

    for (int p = 0; p < N_PLANES; ++p) {
        const float nx = nrm[p*3+0], ny = nrm[p*3+1], nz = nrm[p*3+2];
        const float d  = dst[p];
        const float t0 = fmaf(ox, nx, fmaf(oy, ny, fmaf(oz, nz, -d)));
        const bool  m  = fabsf(t0) < THRESH;
        if (__any(m)) {
            const float rx  = params[p*8+0];
            const float ry  = params[p*8+1];
            const float rz  = params[p*8+2];
            const float rd  = params[p*8+3];
            const float vld = params[p*8+4];
            const float t = fmaf(qx, rx, fmaf(qy, ry, fmaf(qz, rz, -rd)));
            const float f = m ? vld : 0.0f;
            const float ft = f * t;
            qx = fmaf(-ft, rx, qx);
            qy = fmaf(-ft, ry, qy);
            qz = fmaf(-ft, rz, qz);
        }
    }

    out[i*3+0] = qx;
    out[i*3+1] = qy;
    out[i*3+2] = qz;
}

// ---------------------------------------------------------------------------
extern "C" void kernel_launch(void* const* d_in, const int* in_sizes, int n_in,
                              void* d_out, int out_size, void* d_ws, size_t ws_size,
                              hipStream_t stream)
{
    const float* pts = (const float*)d_in[0];
    const float* nrm = (const float*)d_in[1];
    const float* dst = (const float*)d_in[2];
    float* out = (float*)d_out;

    double* acc   = (double*)d_ws;                                   // 64*10 f64 = 5120 B
    float* params = (float*)((char*)d_ws + N_PLANES*10*sizeof(double)); // 64*8 f32 = 2048 B

    hipMemsetAsync(d_ws, 0, N_PLANES * 10 * sizeof(double), stream);

    const int b1 = (N_POINTS + 4096 - 1) / 4096;   // 977 blocks, 4096 pts/block
    hipLaunchKernelGGL(reduce_kernel, dim3(b1), dim3(256), 0, stream, pts, nrm, dst, acc);
    hipLaunchKernelGGL(fit_kernel, dim3(1), dim3(64), 0, stream, acc, nrm, params);
    hipLaunchKernelGGL(project_kernel, dim3((N_POINTS + 255) / 256), dim3(256), 0, stream,
                       pts, nrm, dst, params, out);
}

// Round 2
// 885.907 us; speedup vs baseline: 1.0675x; 1.0675x over previous
//
#include <hip/hip_runtime.h>
#include <math.h>

#define N_POINTS 4000000
#define N_PLANES 64
#define THRESH   0.02f
#define PPT      16   // points held in registers per lane -> 1024 points per wave

// ---------------------------------------------------------------------------
// Kernel 1: per-plane masked moment reduction over the ORIGINAL points.
// Fully predicated per-lane accumulation (no serial shuffle walks), then one
// 6-step butterfly per plane and 10 f64 global atomics from lane 0.
// FULL template parameter: hot path (all 16 slots valid) has no tail checks.
// ---------------------------------------------------------------------------
template <bool FULL>
__device__ __forceinline__
void reduce_body(const float* __restrict__ pts,
                 const float* __restrict__ nrm,
                 const float* __restrict__ dst,
                 double* __restrict__ acc,
                 long long base, int lane, int prot)
{
    float px[PPT], py[PPT], pz[PPT];
    unsigned vmask = 0;
#pragma unroll
    for (int j = 0; j < PPT; ++j) {
        const long long idx = base + (long long)j * 64 + lane;
        if (FULL || idx < N_POINTS) {
            px[j] = pts[idx*3+0];
            py[j] = pts[idx*3+1];
            pz[j] = pts[idx*3+2];
            vmask |= (1u << j);
        } else {
            px[j] = 0.0f; py[j] = 0.0f; pz[j] = 0.0f;
        }
    }

    for (int pi = 0; pi < N_PLANES; ++pi) {
        const int p = (pi + prot) & 63;
        const float nx = nrm[p*3+0], ny = nrm[p*3+1], nz = nrm[p*3+2];
        const float d  = dst[p];

        float cnt = 0.0f;
        float sx = 0.0f, sy = 0.0f, sz = 0.0f;
        float xx = 0.0f, xy = 0.0f, xz = 0.0f;
        float yy = 0.0f, yz = 0.0f, zz = 0.0f;

#pragma unroll
        for (int j = 0; j < PPT; ++j) {
            const float t = fmaf(px[j], nx, fmaf(py[j], ny, fmaf(pz[j], nz, -d)));
            bool m = fabsf(t) < THRESH;
            if (!FULL) m = m && ((vmask >> j) & 1u);
            const float fm = m ? 1.0f : 0.0f;
            const float tx = m ? px[j] : 0.0f;
            const float ty = m ? py[j] : 0.0f;
            const float tz = m ? pz[j] : 0.0f;
            cnt += fm;
            sx += tx; sy += ty; sz += tz;
            xx = fmaf(tx, px[j], xx); xy = fmaf(tx, py[j], xy); xz = fmaf(tx, pz[j], xz);
            yy = fmaf(ty, py[j], yy); yz = fmaf(ty, pz[j], yz); zz = fmaf(tz, pz[j], zz);
        }

        // 6-step butterfly reduction across the 64-lane wave
#pragma unroll
        for (int off = 32; off; off >>= 1) {
            cnt += __shfl_xor(cnt, off);
            sx  += __shfl_xor(sx,  off);
            sy  += __shfl_xor(sy,  off);
            sz  += __shfl_xor(sz,  off);
            xx  += __shfl_xor(xx,  off);
            xy  += __shfl_xor(xy,  off);
            xz  += __shfl_xor(xz,  off);
            yy  += __shfl_xor(yy,  off);
            yz  += __shfl_xor(yz,  off);
            zz  += __shfl_xor(zz,  off);
        }

        if (lane == 0) {
            double* a = acc + p * 10;
            atomicAdd(a+0, (double)cnt);
            atomicAdd(a+1, (double)sx); atomicAdd(a+2, (double)sy); atomicAdd(a+3, (double)sz);
            atomicAdd(a+4, (double)xx); atomicAdd(a+5, (double)xy); atomicAdd(a+6, (double)xz);
            atomicAdd(a+7, (double)yy); atomicAdd(a+8, (double)yz); atomicAdd(a+9, (double)zz);
        }
    }
}

__global__ __launch_bounds__(256)
void reduce_kernel(const float* __restrict__ pts,
                   const float* __restrict__ nrm,
                   const float* __restrict__ dst,
                   double* __restrict__ acc)
{
    const int lane = threadIdx.x & 63;
    const int wid  = threadIdx.x >> 6;
    const long long wave = (long long)blockIdx.x * 4 + wid;
    const long long base = wave * (64LL * PPT);
    const int prot = (int)(blockIdx.x & 63);

    if (base + 64LL * PPT <= N_POINTS)
        reduce_body<true >(pts, nrm, dst, acc, base, lane, prot);
    else
        reduce_body<false>(pts, nrm, dst, acc, base, lane, prot);
}

// ---------------------------------------------------------------------------
// Kernel 2: 64 independent 3x3 symmetric eigensolves (f64 cyclic Jacobi).
// ---------------------------------------------------------------------------
__global__ void fit_kernel(const double* __restrict__ acc,
                           const float* __restrict__ nrm,
                           float* __restrict__ params)
{
    const int p = threadIdx.x;
    if (p >= N_PLANES) return;

    const double* a = acc + p * 10;
    const double cnt = a[0];
    const double sx = a[1], sy = a[2], sz = a[3];
    const double den = fmax(cnt, 1.0);
    const double cx = sx / den, cy = sy / den, cz = sz / den;

    double C[3][3];
    C[0][0] = a[4] - 2.0*cx*sx + cnt*cx*cx;
    C[0][1] = a[5] - cx*sy - cy*sx + cnt*cx*cy;
    C[0][2] = a[6] - cx*sz - cz*sx + cnt*cx*cz;
    C[1][1] = a[7] - 2.0*cy*sy + cnt*cy*cy;
    C[1][2] = a[8] - cy*sz - cz*sy + cnt*cy*cz;
    C[2][2] = a[9] - 2.0*cz*sz + cnt*cz*cz;
    C[1][0] = C[0][1]; C[2][0] = C[0][2]; C[2][1] = C[1][2];

    const double valid = (cnt >= 3.0) ? 1.0 : 0.0;
    C[0][0] += (1.0 - valid) * 1.0;
    C[1][1] += (1.0 - valid) * 2.0;
    C[2][2] += (1.0 - valid) * 3.0;

    double V[3][3] = {{1,0,0},{0,1,0},{0,0,1}};
    for (int sweep = 0; sweep < 15; ++sweep) {
#pragma unroll
        for (int k = 0; k < 3; ++k) {
            const int pp = (k == 2) ? 1 : 0;
            const int qq = (k == 0) ? 1 : 2;
            const int rr = 3 - pp - qq;
            const double apq = C[pp][qq];
            if (fabs(apq) < 1e-300) continue;
            const double theta = (C[qq][qq] - C[pp][pp]) / (2.0 * apq);
            const double t = copysign(1.0, theta) / (fabs(theta) + sqrt(theta*theta + 1.0));
            const double c = 1.0 / sqrt(t*t + 1.0);
            const double s = t * c;
            const double app = C[pp][pp], aqq = C[qq][qq];
            const double arp = C[rr][pp], arq = C[rr][qq];
            C[pp][pp] = app - t * apq;
            C[qq][qq] = aqq + t * apq;
            C[pp][qq] = 0.0; C[qq][pp] = 0.0;
            const double nrp = c*arp - s*arq;
            const double nrq = s*arp + c*arq;
            C[rr][pp] = nrp; C[pp][rr] = nrp;
            C[rr][qq] = nrq; C[qq][rr] = nrq;
#pragma unroll
            for (int i = 0; i < 3; ++i) {
                const double vip = V[i][pp], viq = V[i][qq];
                V[i][pp] = c*vip - s*viq;
                V[i][qq] = s*vip + c*viq;
            }
        }
    }

    int idx = 0;
    if (C[1][1] < C[idx][idx]) idx = 1;
    if (C[2][2] < C[idx][idx]) idx = 2;
    double rx = V[0][idx], ry = V[1][idx], rz = V[2][idx];
    const double inv = 1.0 / sqrt(rx*rx + ry*ry + rz*rz);
    rx *= inv; ry *= inv; rz *= inv;

    const double nx = (double)nrm[p*3+0];
    const double ny = (double)nrm[p*3+1];
    const double nz = (double)nrm[p*3+2];
    if (rx*nx + ry*ny + rz*nz < 0.0) { rx = -rx; ry = -ry; rz = -rz; }
    const double rd = cx*rx + cy*ry + cz*rz;

    params[p*8+0] = (float)rx;
    params[p*8+1] = (float)ry;
    params[p*8+2] = (float)rz;
    params[p*8+3] = (float)rd;
    params[p*8+4] = (float)valid;
}

// ---------------------------------------------------------------------------
// Kernel 3: per-point sequential projection across planes 0..63 (branchless).
// Mask from the ORIGINAL point (identical fma expression to kernel 1),
// projection applied cumulatively to the running point.
// ---------------------------------------------------------------------------
__global__ __launch_bounds__(256)
void project_kernel(const float* __restrict__ pts,
                    const float* __restrict__ nrm,
                    const float* __restrict__ dst,
                    const float* __restrict__ params,
                    float* __restrict__ out)
{
    const long long i = (long long)blockIdx.x * 256 + threadIdx.x;
    if (i >= N_POINTS) return;

    const float ox = pts[i*3+0], oy = pts[i*3+1], oz = pts[i*3+2];
    float qx = ox, qy = oy, qz = oz;

#pragma unroll 4
    for (int p = 0; p < N_PLANES; ++p) {
        const float nx = nrm[p*3+0], ny = nrm[p*3+1], nz = nrm[p*3+2];
        const float d  = dst[p];
        const float rx  = params[p*8+0];
        const float ry  = params[p*8+1];
        const float rz  = params[p*8+2];
        const float rd  = params[p*8+3];
        const float vld = params[p*8+4];

        const float t0 = fmaf(ox, nx, fmaf(oy, ny, fmaf(oz, nz, -d)));
        const float f  = (fabsf(t0) < THRESH) ? vld : 0.0f;
        const float t  = fmaf(qx, rx, fmaf(qy, ry, fmaf(qz, rz, -rd)));
        const float ft = f * t;
        qx = fmaf(-ft, rx, qx);
        qy = fmaf(-ft, ry, qy);
        qz = fmaf(-ft, rz, qz);
    }

    out[i*3+0] = qx;
    out[i*3+1] = qy;
    out[i*3+2] = qz;
}

// ---------------------------------------------------------------------------
extern "C" void kernel_launch(void* const* d_in, const int* in_sizes, int n_in,
                              void* d_out, int out_size, void* d_ws, size_t ws_size,
                              hipStream_t stream)
{
    const float* pts = (const float*)d_in[0];
    const float* nrm = (const float*)d_in[1];
    const float* dst = (const float*)d_in[2];
    float* out = (float*)d_out;

    double* acc   = (double*)d_ws;                                      // 64*10 f64
    float* params = (float*)((char*)d_ws + N_PLANES*10*sizeof(double)); // 64*8 f32

    hipMemsetAsync(d_ws, 0, N_PLANES * 10 * sizeof(double), stream);

    const int waves  = (N_POINTS + 64*PPT - 1) / (64*PPT);   // 3907
    const int blocks = (waves + 3) / 4;                      // 977
    hipLaunchKernelGGL(reduce_kernel, dim3(blocks), dim3(256), 0, stream, pts, nrm, dst, acc);
    hipLaunchKernelGGL(fit_kernel, dim3(1), dim3(64), 0, stream, acc, nrm, params);
    hipLaunchKernelGGL(project_kernel, dim3((N_POINTS + 255) / 256), dim3(256), 0, stream,
                       pts, nrm, dst, params, out);
}

// Round 3
// 289.324 us; speedup vs baseline: 3.2688x; 3.0620x over previous
//
#include <hip/hip_runtime.h>
#include <math.h>

#define N_POINTS 4000000
#define N_PLANES 64
#define THRESH   0.02f
#define PPT      32                                   // points per lane per chunk
#define WAVE_PTS (64*PPT)                             // 2048
#define BLK_PTS  (4*WAVE_PTS)                         // 8192
#define NCHUNKS  ((N_POINTS + BLK_PTS - 1)/BLK_PTS)   // 489
#define NVALS    (N_PLANES*10)                        // 640

// ---------------------------------------------------------------------------
// Stage 1: per-plane masked moments, accumulated per-wave in registers,
// butterflied, accumulated into a per-wave LDS row, stored as coalesced
// per-block f32 partials. ZERO global atomics.
// ---------------------------------------------------------------------------
template <bool FULL>
__device__ __forceinline__
void chunk_body(const float* __restrict__ pts,
                const float* __restrict__ nrm,
                const float* __restrict__ dst,
                float* __restrict__ row,              // this wave's LDS row (640 f32)
                long long base, int lane)
{
    float px[PPT], py[PPT], pz[PPT];
    unsigned vmask = 0;
#pragma unroll
    for (int j = 0; j < PPT; ++j) {
        const long long idx = base + (long long)j * 64 + lane;
        if (FULL || idx < N_POINTS) {
            const float* P = pts + idx * 3;
            px[j] = P[0]; py[j] = P[1]; pz[j] = P[2];
            vmask |= (1u << j);
        } else {
            px[j] = 0.0f; py[j] = 0.0f; pz[j] = 0.0f;
        }
    }

    for (int p = 0; p < N_PLANES; ++p) {
        const float nx = nrm[p*3+0], ny = nrm[p*3+1], nz = nrm[p*3+2];
        const float d  = dst[p];

        int icnt = 0;   // wave-uniform count via ballot (scalar pipe)
        float sx=0.f, sy=0.f, sz=0.f;
        float xx=0.f, xy=0.f, xz=0.f, yy=0.f, yz=0.f, zz=0.f;

#pragma unroll
        for (int j = 0; j < PPT; ++j) {
            const float t = fmaf(px[j], nx, fmaf(py[j], ny, fmaf(pz[j], nz, -d)));
            bool m = fabsf(t) < THRESH;
            if (!FULL) m = m && ((vmask >> j) & 1u);
            icnt += (int)__popcll(__ballot(m));
            const float tx = m ? px[j] : 0.0f;
            const float ty = m ? py[j] : 0.0f;
            const float tz = m ? pz[j] : 0.0f;
            sx += tx; sy += ty; sz += tz;
            xx = fmaf(tx, px[j], xx); xy = fmaf(tx, py[j], xy); xz = fmaf(tx, pz[j], xz);
            yy = fmaf(ty, py[j], yy); yz = fmaf(ty, pz[j], yz); zz = fmaf(tz, pz[j], zz);
        }

#pragma unroll
        for (int off = 32; off; off >>= 1) {
            sx += __shfl_xor(sx, off); sy += __shfl_xor(sy, off); sz += __shfl_xor(sz, off);
            xx += __shfl_xor(xx, off); xy += __shfl_xor(xy, off); xz += __shfl_xor(xz, off);
            yy += __shfl_xor(yy, off); yz += __shfl_xor(yz, off); zz += __shfl_xor(zz, off);
        }

        if (lane == 0) {
            float* r = row + p * 10;
            r[0] += (float)icnt;
            r[1] += sx; r[2] += sy; r[3] += sz;
            r[4] += xx; r[5] += xy; r[6] += xz;
            r[7] += yy; r[8] += yz; r[9] += zz;
        }
    }
}

__global__ __launch_bounds__(256, 2)
void reduce_kernel(const float* __restrict__ pts,
                   const float* __restrict__ nrm,
                   const float* __restrict__ dst,
                   float* __restrict__ partials, int nb)
{
    __shared__ float part[4][NVALS];
    float* pf = &part[0][0];
    for (int v = threadIdx.x; v < 4 * NVALS; v += 256) pf[v] = 0.0f;
    __syncthreads();

    const int lane = threadIdx.x & 63;
    const int wid  = threadIdx.x >> 6;

    for (int c = blockIdx.x; c < NCHUNKS; c += nb) {
        const long long base = (long long)c * BLK_PTS + (long long)wid * WAVE_PTS;
        if (base + WAVE_PTS <= N_POINTS)
            chunk_body<true >(pts, nrm, dst, part[wid], base, lane);
        else
            chunk_body<false>(pts, nrm, dst, part[wid], base, lane);
    }

    __syncthreads();
    for (int v = threadIdx.x; v < NVALS; v += 256)
        partials[(long long)blockIdx.x * NVALS + v] =
            part[0][v] + part[1][v] + part[2][v] + part[3][v];
}

// ---------------------------------------------------------------------------
// Stage 2 (fused fit): one block per plane. Stream partials, f64-accumulate,
// then thread 0 runs the 3x3 Jacobi eigensolve and writes {rn, rd, valid}.
// ---------------------------------------------------------------------------
__global__ __launch_bounds__(256)
void finalize_kernel(const float* __restrict__ partials, int nb,
                     const float* __restrict__ nrm,
                     float* __restrict__ params)
{
    const int p    = blockIdx.x;
    const int lane = threadIdx.x & 63;
    const int wid  = threadIdx.x >> 6;

    double s[10];
#pragma unroll
    for (int q = 0; q < 10; ++q) s[q] = 0.0;

    for (int b = threadIdx.x; b < nb; b += 256) {
        const float* row = partials + (long long)b * NVALS + p * 10;
#pragma unroll
        for (int q = 0; q < 10; ++q) s[q] += (double)row[q];
    }

#pragma unroll
    for (int off = 32; off; off >>= 1)
#pragma unroll
        for (int q = 0; q < 10; ++q) s[q] += __shfl_xor(s[q], off);

    __shared__ double wsum[4][10];
    if (lane == 0) {
#pragma unroll
        for (int q = 0; q < 10; ++q) wsum[wid][q] = s[q];
    }
    __syncthreads();
    if (threadIdx.x != 0) return;

    double a[10];
#pragma unroll
    for (int q = 0; q < 10; ++q)
        a[q] = wsum[0][q] + wsum[1][q] + wsum[2][q] + wsum[3][q];

    const double cnt = a[0];
    const double sx = a[1], sy = a[2], sz = a[3];
    const double den = fmax(cnt, 1.0);
    const double cx = sx / den, cy = sy / den, cz = sz / den;

    double C[3][3];
    C[0][0] = a[4] - 2.0*cx*sx + cnt*cx*cx;
    C[0][1] = a[5] - cx*sy - cy*sx + cnt*cx*cy;
    C[0][2] = a[6] - cx*sz - cz*sx + cnt*cx*cz;
    C[1][1] = a[7] - 2.0*cy*sy + cnt*cy*cy;
    C[1][2] = a[8] - cy*sz - cz*sy + cnt*cy*cz;
    C[2][2] = a[9] - 2.0*cz*sz + cnt*cz*cz;
    C[1][0] = C[0][1]; C[2][0] = C[0][2]; C[2][1] = C[1][2];

    const double valid = (cnt >= 3.0) ? 1.0 : 0.0;
    C[0][0] += (1.0 - valid) * 1.0;
    C[1][1] += (1.0 - valid) * 2.0;
    C[2][2] += (1.0 - valid) * 3.0;

    double V[3][3] = {{1,0,0},{0,1,0},{0,0,1}};
    for (int sweep = 0; sweep < 15; ++sweep) {
#pragma unroll
        for (int k = 0; k < 3; ++k) {
            const int pp = (k == 2) ? 1 : 0;
            const int qq = (k == 0) ? 1 : 2;
            const int rr = 3 - pp - qq;
            const double apq = C[pp][qq];
            if (fabs(apq) < 1e-300) continue;
            const double theta = (C[qq][qq] - C[pp][pp]) / (2.0 * apq);
            const double t = copysign(1.0, theta) / (fabs(theta) + sqrt(theta*theta + 1.0));
            const double c = 1.0 / sqrt(t*t + 1.0);
            const double ss = t * c;
            const double app = C[pp][pp], aqq = C[qq][qq];
            const double arp = C[rr][pp], arq = C[rr][qq];
            C[pp][pp] = app - t * apq;
            C[qq][qq] = aqq + t * apq;
            C[pp][qq] = 0.0; C[qq][pp] = 0.0;
            const double nrp = c*arp - ss*arq;
            const double nrq = ss*arp + c*arq;
            C[rr][pp] = nrp; C[pp][rr] = nrp;
            C[rr][qq] = nrq; C[qq][rr] = nrq;
#pragma unroll
            for (int i = 0; i < 3; ++i) {
                const double vip = V[i][pp], viq = V[i][qq];
                V[i][pp] = c*vip - ss*viq;
                V[i][qq] = ss*vip + c*viq;
            }
        }
    }

    int idx = 0;
    if (C[1][1] < C[idx][idx]) idx = 1;
    if (C[2][2] < C[idx][idx]) idx = 2;
    double rx = V[0][idx], ry = V[1][idx], rz = V[2][idx];
    const double inv = 1.0 / sqrt(rx*rx + ry*ry + rz*rz);
    rx *= inv; ry *= inv; rz *= inv;

    const double nx = (double)nrm[p*3+0];
    const double ny = (double)nrm[p*3+1];
    const double nz = (double)nrm[p*3+2];
    if (rx*nx + ry*ny + rz*nz < 0.0) { rx = -rx; ry = -ry; rz = -rz; }
    const double rd = cx*rx + cy*ry + cz*rz;

    params[p*8+0] = (float)rx;
    params[p*8+1] = (float)ry;
    params[p*8+2] = (float)rz;
    params[p*8+3] = (float)rd;
    params[p*8+4] = (float)valid;
}

// ---------------------------------------------------------------------------
// Stage 3: per-point sequential projection across planes 0..63 (branchless).
// Mask from the ORIGINAL point (identical fma expression to stage 1).
// ---------------------------------------------------------------------------
__global__ __launch_bounds__(256)
void project_kernel(const float* __restrict__ pts,
                    const float* __restrict__ nrm,
                    const float* __restrict__ dst,
                    const float* __restrict__ params,
                    float* __restrict__ out)
{
    const long long i = (long long)blockIdx.x * 256 + threadIdx.x;
    if (i >= N_POINTS) return;

    const float ox = pts[i*3+0], oy = pts[i*3+1], oz = pts[i*3+2];
    float qx = ox, qy = oy, qz = oz;

#pragma unroll 4
    for (int p = 0; p < N_PLANES; ++p) {
        const float nx = nrm[p*3+0], ny = nrm[p*3+1], nz = nrm[p*3+2];
        const float d  = dst[p];
        const float rx  = params[p*8+0];
        const float ry  = params[p*8+1];
        const float rz  = params[p*8+2];
        const float rd  = params[p*8+3];
        const float vld = params[p*8+4];

        const float t0 = fmaf(ox, nx, fmaf(oy, ny, fmaf(oz, nz, -d)));
        const float f  = (fabsf(t0) < THRESH) ? vld : 0.0f;
        const float t  = fmaf(qx, rx, fmaf(qy, ry, fmaf(qz, rz, -rd)));
        const float ft = f * t;
        qx = fmaf(-ft, rx, qx);
        qy = fmaf(-ft, ry, qy);
        qz = fmaf(-ft, rz, qz);
    }

    out[i*3+0] = qx;
    out[i*3+1] = qy;
    out[i*3+2] = qz;
}

// ---------------------------------------------------------------------------
extern "C" void kernel_launch(void* const* d_in, const int* in_sizes, int n_in,
                              void* d_out, int out_size, void* d_ws, size_t ws_size,
                              hipStream_t stream)
{
    const float* pts = (const float*)d_in[0];
    const float* nrm = (const float*)d_in[1];
    const float* dst = (const float*)d_in[2];
    float* out = (float*)d_out;

    // size the partial grid to the available scratch (2560 B per block row)
    size_t avail = (ws_size > 4096) ? (ws_size - 4096) : 0;
    int nb = (int)(avail / (NVALS * sizeof(float)));
    if (nb < 1) nb = 1;
    if (nb > NCHUNKS) nb = NCHUNKS;

    float* partials = (float*)d_ws;
    size_t poff = ((size_t)nb * NVALS * sizeof(float) + 255) & ~(size_t)255;
    float* params = (float*)((char*)d_ws + poff);

    hipLaunchKernelGGL(reduce_kernel, dim3(nb), dim3(256), 0, stream,
                       pts, nrm, dst, partials, nb);
    hipLaunchKernelGGL(finalize_kernel, dim3(N_PLANES), dim3(256), 0, stream,
                       partials, nb, nrm, params);
    hipLaunchKernelGGL(project_kernel, dim3((N_POINTS + 255) / 256), dim3(256), 0, stream,
                       pts, nrm, dst, params, out);
}

// Round 4
// 239.605 us; speedup vs baseline: 3.9471x; 1.2075x over previous
//
#include <hip/hip_runtime.h>
#include <math.h>

#define N_POINTS 4000000
#define N_PLANES 64
#define THRESH   0.02f
#define NVALS    (N_PLANES*10)   // 640
#define RBLOCKS  512             // reduce grid (per-block partial = 2560 B)
#define RTHREADS 512             // 8 waves per block

// ---------------------------------------------------------------------------
// Stage 1: plane-per-lane moment reduction.
// lane = plane id; the wave streams a contiguous range of points whose
// coordinates are wave-uniform (scalarized to s_load via readfirstlane).
// Each lane accumulates its plane's 10 masked moments in registers for the
// whole kernel; one LDS combine per block at the end. No shuffles, no atomics.
// ---------------------------------------------------------------------------
__global__ __launch_bounds__(RTHREADS)
void reduce_kernel(const float* __restrict__ pts,
                   const float* __restrict__ nrm,
                   const float* __restrict__ dst,
                   float* __restrict__ partials, int ppw)
{
    const int lane = threadIdx.x & 63;
    const int wid  = __builtin_amdgcn_readfirstlane((int)(threadIdx.x >> 6));
    const int gwave = blockIdx.x * (RTHREADS / 64) + wid;

    // per-lane plane parameters (lane == plane index)
    const float nx = nrm[lane*3+0];
    const float ny = nrm[lane*3+1];
    const float nz = nrm[lane*3+2];
    const float nd = -dst[lane];

    float cnt=0.f, sx=0.f, sy=0.f, sz=0.f;
    float xx=0.f, xy=0.f, xz=0.f, yy=0.f, yz=0.f, zz=0.f;

    long long beg = (long long)gwave * ppw;
    long long end = beg + ppw;
    if (beg > N_POINTS) beg = N_POINTS;
    if (end > N_POINTS) end = N_POINTS;

    long long j = beg;
    for (; j + 8 <= end; j += 8) {
#pragma unroll
        for (int u = 0; u < 8; ++u) {
            const float x = pts[(j+u)*3+0];   // wave-uniform -> s_load
            const float y = pts[(j+u)*3+1];
            const float z = pts[(j+u)*3+2];
            const float t  = fmaf(x, nx, fmaf(y, ny, fmaf(z, nz, nd)));
            const float fm = (fabsf(t) < THRESH) ? 1.0f : 0.0f;
            const float tx = fm * x, ty = fm * y, tz = fm * z;
            cnt += fm;
            sx += tx; sy += ty; sz += tz;
            xx = fmaf(tx, x, xx); xy = fmaf(tx, y, xy); xz = fmaf(tx, z, xz);
            yy = fmaf(ty, y, yy); yz = fmaf(ty, z, yz); zz = fmaf(tz, z, zz);
        }
    }
    for (; j < end; ++j) {
        const float x = pts[j*3+0];
        const float y = pts[j*3+1];
        const float z = pts[j*3+2];
        const float t  = fmaf(x, nx, fmaf(y, ny, fmaf(z, nz, nd)));
        const float fm = (fabsf(t) < THRESH) ? 1.0f : 0.0f;
        const float tx = fm * x, ty = fm * y, tz = fm * z;
        cnt += fm;
        sx += tx; sy += ty; sz += tz;
        xx = fmaf(tx, x, xx); xy = fmaf(tx, y, xy); xz = fmaf(tx, z, xz);
        yy = fmaf(ty, y, yy); yz = fmaf(ty, z, yz); zz = fmaf(tz, z, zz);
    }

    // block combine: 8 per-wave rows -> 1 per-block row of 640 f32
    __shared__ float part[RTHREADS/64][NVALS];
    {
        float* r = &part[threadIdx.x >> 6][lane * 10];
        r[0]=cnt; r[1]=sx; r[2]=sy; r[3]=sz;
        r[4]=xx; r[5]=xy; r[6]=xz; r[7]=yy; r[8]=yz; r[9]=zz;
    }
    __syncthreads();
    for (int v = threadIdx.x; v < NVALS; v += RTHREADS) {
        float s = 0.f;
#pragma unroll
        for (int w = 0; w < RTHREADS/64; ++w) s += part[w][v];
        partials[(long long)blockIdx.x * NVALS + v] = s;
    }
}

// ---------------------------------------------------------------------------
// Stage 2 (fused fit): one block per plane. Stream partials, f64-accumulate,
// thread 0 runs the 3x3 Jacobi eigensolve and writes {rn, rd, valid}.
// ---------------------------------------------------------------------------
__global__ __launch_bounds__(256)
void finalize_kernel(const float* __restrict__ partials, int nb,
                     const float* __restrict__ nrm,
                     float* __restrict__ params)
{
    const int p    = blockIdx.x;
    const int lane = threadIdx.x & 63;
    const int wid  = threadIdx.x >> 6;

    double s[10];
#pragma unroll
    for (int q = 0; q < 10; ++q) s[q] = 0.0;

    for (int b = threadIdx.x; b < nb; b += 256) {
        const float* row = partials + (long long)b * NVALS + p * 10;
#pragma unroll
        for (int q = 0; q < 10; ++q) s[q] += (double)row[q];
    }

#pragma unroll
    for (int off = 32; off; off >>= 1)
#pragma unroll
        for (int q = 0; q < 10; ++q) s[q] += __shfl_xor(s[q], off);

    __shared__ double wsum[4][10];
    if (lane == 0) {
#pragma unroll
        for (int q = 0; q < 10; ++q) wsum[wid][q] = s[q];
    }
    __syncthreads();
    if (threadIdx.x != 0) return;

    double a[10];
#pragma unroll
    for (int q = 0; q < 10; ++q)
        a[q] = wsum[0][q] + wsum[1][q] + wsum[2][q] + wsum[3][q];

    const double cnt = a[0];
    const double sx = a[1], sy = a[2], sz = a[3];
    const double den = fmax(cnt, 1.0);
    const double cx = sx / den, cy = sy / den, cz = sz / den;

    double C[3][3];
    C[0][0] = a[4] - 2.0*cx*sx + cnt*cx*cx;
    C[0][1] = a[5] - cx*sy - cy*sx + cnt*cx*cy;
    C[0][2] = a[6] - cx*sz - cz*sx + cnt*cx*cz;
    C[1][1] = a[7] - 2.0*cy*sy + cnt*cy*cy;
    C[1][2] = a[8] - cy*sz - cz*sy + cnt*cy*cz;
    C[2][2] = a[9] - 2.0*cz*sz + cnt*cz*cz;
    C[1][0] = C[0][1]; C[2][0] = C[0][2]; C[2][1] = C[1][2];

    const double valid = (cnt >= 3.0) ? 1.0 : 0.0;
    C[0][0] += (1.0 - valid) * 1.0;
    C[1][1] += (1.0 - valid) * 2.0;
    C[2][2] += (1.0 - valid) * 3.0;

    double V[3][3] = {{1,0,0},{0,1,0},{0,0,1}};
    for (int sweep = 0; sweep < 15; ++sweep) {
#pragma unroll
        for (int k = 0; k < 3; ++k) {
            const int pp = (k == 2) ? 1 : 0;
            const int qq = (k == 0) ? 1 : 2;
            const int rr = 3 - pp - qq;
            const double apq = C[pp][qq];
            if (fabs(apq) < 1e-300) continue;
            const double theta = (C[qq][qq] - C[pp][pp]) / (2.0 * apq);
            const double t = copysign(1.0, theta) / (fabs(theta) + sqrt(theta*theta + 1.0));
            const double c = 1.0 / sqrt(t*t + 1.0);
            const double ss = t * c;
            const double app = C[pp][pp], aqq = C[qq][qq];
            const double arp = C[rr][pp], arq = C[rr][qq];
            C[pp][pp] = app - t * apq;
            C[qq][qq] = aqq + t * apq;
            C[pp][qq] = 0.0; C[qq][pp] = 0.0;
            const double nrp = c*arp - ss*arq;
            const double nrq = ss*arp + c*arq;
            C[rr][pp] = nrp; C[pp][rr] = nrp;
            C[rr][qq] = nrq; C[qq][rr] = nrq;
#pragma unroll
            for (int i = 0; i < 3; ++i) {
                const double vip = V[i][pp], viq = V[i][qq];
                V[i][pp] = c*vip - ss*viq;
                V[i][qq] = ss*vip + c*viq;
            }
        }
    }

    int idx = 0;
    if (C[1][1] < C[idx][idx]) idx = 1;
    if (C[2][2] < C[idx][idx]) idx = 2;
    double rx = V[0][idx], ry = V[1][idx], rz = V[2][idx];
    const double inv = 1.0 / sqrt(rx*rx + ry*ry + rz*rz);
    rx *= inv; ry *= inv; rz *= inv;

    const double nxd = (double)nrm[p*3+0];
    const double nyd = (double)nrm[p*3+1];
    const double nzd = (double)nrm[p*3+2];
    if (rx*nxd + ry*nyd + rz*nzd < 0.0) { rx = -rx; ry = -ry; rz = -rz; }
    const double rd = cx*rx + cy*ry + cz*rz;

    params[p*8+0] = (float)rx;
    params[p*8+1] = (float)ry;
    params[p*8+2] = (float)rz;
    params[p*8+3] = (float)rd;
    params[p*8+4] = (float)valid;
}

// ---------------------------------------------------------------------------
// Stage 3: per-point sequential projection across planes 0..63 (branchless).
// ---------------------------------------------------------------------------
__global__ __launch_bounds__(256)
void project_kernel(const float* __restrict__ pts,
                    const float* __restrict__ nrm,
                    const float* __restrict__ dst,
                    const float* __restrict__ params,
                    float* __restrict__ out)
{
    const long long i = (long long)blockIdx.x * 256 + threadIdx.x;
    if (i >= N_POINTS) return;

    const float ox = pts[i*3+0], oy = pts[i*3+1], oz = pts[i*3+2];
    float qx = ox, qy = oy, qz = oz;

#pragma unroll 4
    for (int p = 0; p < N_PLANES; ++p) {
        const float nx = nrm[p*3+0], ny = nrm[p*3+1], nz = nrm[p*3+2];
        const float d  = dst[p];
        const float rx  = params[p*8+0];
        const float ry  = params[p*8+1];
        const float rz  = params[p*8+2];
        const float rd  = params[p*8+3];
        const float vld = params[p*8+4];

        const float t0 = fmaf(ox, nx, fmaf(oy, ny, fmaf(oz, nz, -d)));
        const float f  = (fabsf(t0) < THRESH) ? vld : 0.0f;
        const float t  = fmaf(qx, rx, fmaf(qy, ry, fmaf(qz, rz, -rd)));
        const float ft = f * t;
        qx = fmaf(-ft, rx, qx);
        qy = fmaf(-ft, ry, qy);
        qz = fmaf(-ft, rz, qz);
    }

    out[i*3+0] = qx;
    out[i*3+1] = qy;
    out[i*3+2] = qz;
}

// ---------------------------------------------------------------------------
extern "C" void kernel_launch(void* const* d_in, const int* in_sizes, int n_in,
                              void* d_out, int out_size, void* d_ws, size_t ws_size,
                              hipStream_t stream)
{
    const float* pts = (const float*)d_in[0];
    const float* nrm = (const float*)d_in[1];
    const float* dst = (const float*)d_in[2];
    float* out = (float*)d_out;

    // size the reduce grid to the available scratch (2560 B per block row)
    size_t avail = (ws_size > 4096) ? (ws_size - 4096) : 0;
    int nb = (int)(avail / (NVALS * sizeof(float)));
    if (nb < 1) nb = 1;
    if (nb > RBLOCKS) nb = RBLOCKS;

    float* partials = (float*)d_ws;
    size_t poff = ((size_t)nb * NVALS * sizeof(float) + 255) & ~(size_t)255;
    float* params = (float*)((char*)d_ws + poff);

    const int nwaves = nb * (RTHREADS / 64);
    const int ppw = (int)((N_POINTS + nwaves - 1) / nwaves);

    hipLaunchKernelGGL(reduce_kernel, dim3(nb), dim3(RTHREADS), 0, stream,
                       pts, nrm, dst, partials, ppw);
    hipLaunchKernelGGL(finalize_kernel, dim3(N_PLANES), dim3(256), 0, stream,
                       partials, nb, nrm, params);
    hipLaunchKernelGGL(project_kernel, dim3((N_POINTS + 255) / 256), dim3(256), 0, stream,
                       pts, nrm, dst, params, out);
}

// Round 5
// 201.421 us; speedup vs baseline: 4.6953x; 1.1896x over previous
//
#include <hip/hip_runtime.h>
#include <math.h>

#define N_POINTS 4000000
#define N_PLANES 64
#define THRESH   0.02f
#define NVALS    (N_PLANES*10)   // 640
#define RBLOCKS  1024            // reduce grid cap (2560 B partial per block)
#define RTHREADS 512             // 8 waves per block
#define UB       16              // point batch per inner iteration

// ---------------------------------------------------------------------------
// Stage 1: plane-per-lane moment reduction.
// lane = plane id; the wave streams contiguous points whose coordinates are
// wave-uniform (scalarized to s_load). Batch-load 16 points into locals, then
// run the 18-op predicated accumulation per point. One LDS combine per block.
// ---------------------------------------------------------------------------
__global__ __launch_bounds__(RTHREADS)
void reduce_kernel(const float* __restrict__ pts,
                   const float* __restrict__ nrm,
                   const float* __restrict__ dst,
                   float* __restrict__ partials, int ppw)
{
    const int lane = threadIdx.x & 63;
    const int wid  = __builtin_amdgcn_readfirstlane((int)(threadIdx.x >> 6));
    const int gwave = blockIdx.x * (RTHREADS / 64) + wid;

    // per-lane plane parameters (lane == plane index)
    const float nx = nrm[lane*3+0];
    const float ny = nrm[lane*3+1];
    const float nz = nrm[lane*3+2];
    const float nd = -dst[lane];

    float cnt=0.f, sx=0.f, sy=0.f, sz=0.f;
    float xx=0.f, xy=0.f, xz=0.f, yy=0.f, yz=0.f, zz=0.f;

    long long beg = (long long)gwave * ppw;
    long long end = beg + ppw;
    if (beg > N_POINTS) beg = N_POINTS;
    if (end > N_POINTS) end = N_POINTS;

    long long j = beg;
    for (; j + UB <= end; j += UB) {
        float X[UB], Y[UB], Z[UB];
#pragma unroll
        for (int u = 0; u < UB; ++u) {
            X[u] = pts[(j+u)*3+0];   // wave-uniform -> s_load batch
            Y[u] = pts[(j+u)*3+1];
            Z[u] = pts[(j+u)*3+2];
        }
#pragma unroll
        for (int u = 0; u < UB; ++u) {
            const float t  = fmaf(X[u], nx, fmaf(Y[u], ny, fmaf(Z[u], nz, nd)));
            const float fm = (fabsf(t) < THRESH) ? 1.0f : 0.0f;
            const float tx = fm * X[u], ty = fm * Y[u], tz = fm * Z[u];
            cnt += fm;
            sx += tx; sy += ty; sz += tz;
            xx = fmaf(tx, X[u], xx); xy = fmaf(tx, Y[u], xy); xz = fmaf(tx, Z[u], xz);
            yy = fmaf(ty, Y[u], yy); yz = fmaf(ty, Z[u], yz); zz = fmaf(tz, Z[u], zz);
        }
    }
    for (; j < end; ++j) {
        const float x = pts[j*3+0];
        const float y = pts[j*3+1];
        const float z = pts[j*3+2];
        const float t  = fmaf(x, nx, fmaf(y, ny, fmaf(z, nz, nd)));
        const float fm = (fabsf(t) < THRESH) ? 1.0f : 0.0f;
        const float tx = fm * x, ty = fm * y, tz = fm * z;
        cnt += fm;
        sx += tx; sy += ty; sz += tz;
        xx = fmaf(tx, x, xx); xy = fmaf(tx, y, xy); xz = fmaf(tx, z, xz);
        yy = fmaf(ty, y, yy); yz = fmaf(ty, z, yz); zz = fmaf(tz, z, zz);
    }

    // block combine: 8 per-wave rows -> 1 per-block row of 640 f32
    __shared__ float part[RTHREADS/64][NVALS];
    {
        float* r = &part[threadIdx.x >> 6][lane * 10];
        r[0]=cnt; r[1]=sx; r[2]=sy; r[3]=sz;
        r[4]=xx; r[5]=xy; r[6]=xz; r[7]=yy; r[8]=yz; r[9]=zz;
    }
    __syncthreads();
    for (int v = threadIdx.x; v < NVALS; v += RTHREADS) {
        float s = 0.f;
#pragma unroll
        for (int w = 0; w < RTHREADS/64; ++w) s += part[w][v];
        partials[(long long)blockIdx.x * NVALS + v] = s;
    }
}

// ---------------------------------------------------------------------------
// Stage 2 (fused fit): one block per plane. Stream partials, f64-accumulate,
// thread 0 runs the 3x3 Jacobi eigensolve and writes the merged param row:
//   {nx, ny, nz, -d, vld*rx, vld*ry, vld*rz, -vld*rd}
// ---------------------------------------------------------------------------
__global__ __launch_bounds__(256)
void finalize_kernel(const float* __restrict__ partials, int nb,
                     const float* __restrict__ nrm,
                     const float* __restrict__ dst,
                     float* __restrict__ params)
{
    const int p    = blockIdx.x;
    const int lane = threadIdx.x & 63;
    const int wid  = threadIdx.x >> 6;

    double s[10];
#pragma unroll
    for (int q = 0; q < 10; ++q) s[q] = 0.0;

    for (int b = threadIdx.x; b < nb; b += 256) {
        const float* row = partials + (long long)b * NVALS + p * 10;
#pragma unroll
        for (int q = 0; q < 10; ++q) s[q] += (double)row[q];
    }

#pragma unroll
    for (int off = 32; off; off >>= 1)
#pragma unroll
        for (int q = 0; q < 10; ++q) s[q] += __shfl_xor(s[q], off);

    __shared__ double wsum[4][10];
    if (lane == 0) {
#pragma unroll
        for (int q = 0; q < 10; ++q) wsum[wid][q] = s[q];
    }
    __syncthreads();
    if (threadIdx.x != 0) return;

    double a[10];
#pragma unroll
    for (int q = 0; q < 10; ++q)
        a[q] = wsum[0][q] + wsum[1][q] + wsum[2][q] + wsum[3][q];

    const double cnt = a[0];
    const double sx = a[1], sy = a[2], sz = a[3];
    const double den = fmax(cnt, 1.0);
    const double cx = sx / den, cy = sy / den, cz = sz / den;

    double C[3][3];
    C[0][0] = a[4] - 2.0*cx*sx + cnt*cx*cx;
    C[0][1] = a[5] - cx*sy - cy*sx + cnt*cx*cy;
    C[0][2] = a[6] - cx*sz - cz*sx + cnt*cx*cz;
    C[1][1] = a[7] - 2.0*cy*sy + cnt*cy*cy;
    C[1][2] = a[8] - cy*sz - cz*sy + cnt*cy*cz;
    C[2][2] = a[9] - 2.0*cz*sz + cnt*cz*cz;
    C[1][0] = C[0][1]; C[2][0] = C[0][2]; C[2][1] = C[1][2];

    const double valid = (cnt >= 3.0) ? 1.0 : 0.0;
    C[0][0] += (1.0 - valid) * 1.0;
    C[1][1] += (1.0 - valid) * 2.0;
    C[2][2] += (1.0 - valid) * 3.0;

    double V[3][3] = {{1,0,0},{0,1,0},{0,0,1}};
    for (int sweep = 0; sweep < 15; ++sweep) {
#pragma unroll
        for (int k = 0; k < 3; ++k) {
            const int pp = (k == 2) ? 1 : 0;
            const int qq = (k == 0) ? 1 : 2;
            const int rr = 3 - pp - qq;
            const double apq = C[pp][qq];
            if (fabs(apq) < 1e-300) continue;
            const double theta = (C[qq][qq] - C[pp][pp]) / (2.0 * apq);
            const double t = copysign(1.0, theta) / (fabs(theta) + sqrt(theta*theta + 1.0));
            const double c = 1.0 / sqrt(t*t + 1.0);
            const double ss = t * c;
            const double app = C[pp][pp], aqq = C[qq][qq];
            const double arp = C[rr][pp], arq = C[rr][qq];
            C[pp][pp] = app - t * apq;
            C[qq][qq] = aqq + t * apq;
            C[pp][qq] = 0.0; C[qq][pp] = 0.0;
            const double nrp = c*arp - ss*arq;
            const double nrq = ss*arp + c*arq;
            C[rr][pp] = nrp; C[pp][rr] = nrp;
            C[rr][qq] = nrq; C[qq][rr] = nrq;
#pragma unroll
            for (int i = 0; i < 3; ++i) {
                const double vip = V[i][pp], viq = V[i][qq];
                V[i][pp] = c*vip - ss*viq;
                V[i][qq] = ss*vip + c*viq;
            }
        }
    }

    int idx = 0;
    if (C[1][1] < C[idx][idx]) idx = 1;
    if (C[2][2] < C[idx][idx]) idx = 2;
    double rx = V[0][idx], ry = V[1][idx], rz = V[2][idx];
    const double inv = 1.0 / sqrt(rx*rx + ry*ry + rz*rz);
    rx *= inv; ry *= inv; rz *= inv;

    const double nxd = (double)nrm[p*3+0];
    const double nyd = (double)nrm[p*3+1];
    const double nzd = (double)nrm[p*3+2];
    if (rx*nxd + ry*nyd + rz*nzd < 0.0) { rx = -rx; ry = -ry; rz = -rz; }
    const double rd = cx*rx + cy*ry + cz*rz;

    const float vldf = (float)valid;
    params[p*8+0] = nrm[p*3+0];
    params[p*8+1] = nrm[p*3+1];
    params[p*8+2] = nrm[p*3+2];
    params[p*8+3] = -dst[p];
    params[p*8+4] = vldf * (float)rx;
    params[p*8+5] = vldf * (float)ry;
    params[p*8+6] = vldf * (float)rz;
    params[p*8+7] = -(vldf * (float)rd);
}

// ---------------------------------------------------------------------------
// Stage 3: projection, 4 points per thread (ILP + amortized param s_loads).
// Mask expression bit-identical to stage 1. vld folded into rv / rdv.
// ---------------------------------------------------------------------------
#define PPTH 4
#define PQ   (N_POINTS / PPTH)   // 1,000,000

__global__ __launch_bounds__(256)
void project_kernel(const float* __restrict__ pts,
                    const float* __restrict__ params,
                    float* __restrict__ out)
{
    const int tid = blockIdx.x * 256 + threadIdx.x;
    if (tid >= PQ) return;

    float ox[PPTH], oy[PPTH], oz[PPTH];
    float qx[PPTH], qy[PPTH], qz[PPTH];
#pragma unroll
    for (int k = 0; k < PPTH; ++k) {
        const long long i = (long long)tid + (long long)k * PQ;
        ox[k] = pts[i*3+0]; oy[k] = pts[i*3+1]; oz[k] = pts[i*3+2];
        qx[k] = ox[k]; qy[k] = oy[k]; qz[k] = oz[k];
    }

#pragma unroll 2
    for (int p = 0; p < N_PLANES; ++p) {
        const float nx  = params[p*8+0];
        const float ny  = params[p*8+1];
        const float nz  = params[p*8+2];
        const float md  = params[p*8+3];   // -d
        const float rvx = params[p*8+4];   // vld*rx
        const float rvy = params[p*8+5];
        const float rvz = params[p*8+6];
        const float mrd = params[p*8+7];   // -vld*rd

#pragma unroll
        for (int k = 0; k < PPTH; ++k) {
            const float t0 = fmaf(ox[k], nx, fmaf(oy[k], ny, fmaf(oz[k], nz, md)));
            const float t  = fmaf(qx[k], rvx, fmaf(qy[k], rvy, fmaf(qz[k], rvz, mrd)));
            const float tm = (fabsf(t0) < THRESH) ? t : 0.0f;
            qx[k] = fmaf(-tm, rvx, qx[k]);
            qy[k] = fmaf(-tm, rvy, qy[k]);
            qz[k] = fmaf(-tm, rvz, qz[k]);
        }
    }

#pragma unroll
    for (int k = 0; k < PPTH; ++k) {
        const long long i = (long long)tid + (long long)k * PQ;
        out[i*3+0] = qx[k];
        out[i*3+1] = qy[k];
        out[i*3+2] = qz[k];
    }
}

// ---------------------------------------------------------------------------
extern "C" void kernel_launch(void* const* d_in, const int* in_sizes, int n_in,
                              void* d_out, int out_size, void* d_ws, size_t ws_size,
                              hipStream_t stream)
{
    const float* pts = (const float*)d_in[0];
    const float* nrm = (const float*)d_in[1];
    const float* dst = (const float*)d_in[2];
    float* out = (float*)d_out;

    // size the reduce grid to the available scratch (2560 B per block row)
    size_t avail = (ws_size > 8192) ? (ws_size - 8192) : 0;
    int nb = (int)(avail / (NVALS * sizeof(float)));
    if (nb < 1) nb = 1;
    if (nb > RBLOCKS) nb = RBLOCKS;

    float* partials = (float*)d_ws;
    size_t poff = ((size_t)nb * NVALS * sizeof(float) + 255) & ~(size_t)255;
    float* params = (float*)((char*)d_ws + poff);

    const int nwaves = nb * (RTHREADS / 64);
    const int ppw = (int)((N_POINTS + nwaves - 1) / nwaves);

    hipLaunchKernelGGL(reduce_kernel, dim3(nb), dim3(RTHREADS), 0, stream,
                       pts, nrm, dst, partials, ppw);
    hipLaunchKernelGGL(finalize_kernel, dim3(N_PLANES), dim3(256), 0, stream,
                       partials, nb, nrm, dst, params);
    hipLaunchKernelGGL(project_kernel, dim3((PQ + 255) / 256), dim3(256), 0, stream,
                       pts, params, out);
}